// Round 8
// baseline (238.941 us; speedup 1.0000x reference)
//
#include <hip/hip_runtime.h>
#include <stdint.h>
#include <math.h>

typedef int v4i  __attribute__((ext_vector_type(4)));
typedef int v16i __attribute__((ext_vector_type(16)));

#define NIMG 16
#define NCH  256
#define HW   3136          // 56*56
#define NPIX 50176         // 16*3136
#define PADH 58
#define NKT  72            // 2304/32
#define NCOT 8             // 256/32
#define WELEMS 589824      // 256*256*3*3

// workspace layout (bytes)
#define A0_OFF   0
#define A0_BYTES (16*58*58*256)          // padded NHWC int8 acts
#define WP0_OFF  (A0_OFF + A0_BYTES)
#define WP_BYTES (NKT*NCOT*64*16)        // 589,824 packed weight frags
#define WP1_OFF  (WP0_OFF + WP_BYTES)
#define COEF_OFF (WP1_OFF + WP_BYTES)    // floats A0[256] B0[256] A1[256] B1[256] scale0 scale1
#define MAXW_OFF (COEF_OFF + 4352)       // 2 x u32
#define SUM1_OFF (MAXW_OFF + 32)         // 512 x u64
#define PART_OFF (SUM1_OFF + 4096)       // 4096 x double2 (bn0 per-plane partials)

typedef __attribute__((address_space(1))) const unsigned int gu32;
typedef __attribute__((address_space(3))) unsigned int lu32;
__device__ __forceinline__ void gll16(const void* g, void* l) {
    __builtin_amdgcn_global_load_lds((gu32*)g, (lu32*)l, 16, 0, 0);
}

// bn0 stage 1: per-(n,c)-plane sum/sumsq in double, one block per plane.
__global__ __launch_bounds__(256) void bn0_part(const float* __restrict__ X,
        double2* __restrict__ part, unsigned* __restrict__ maxw,
        unsigned long long* __restrict__ sums) {
    if (blockIdx.x == 0) {
        int t = threadIdx.x;
        if (t < 2) maxw[t] = 0u;
        for (int i = t; i < 512; i += 256) sums[i] = 0ull;
    }
    int p = blockIdx.x;                    // n*256 + c
    const float4* src = (const float4*)(X + (size_t)p * HW);
    double s = 0.0, s2 = 0.0;
    for (int i = threadIdx.x; i < HW / 4; i += 256) {
        float4 v = src[i];
        s  += (double)v.x + (double)v.y + (double)v.z + (double)v.w;
        s2 += (double)v.x * (double)v.x + (double)v.y * (double)v.y
            + (double)v.z * (double)v.z + (double)v.w * (double)v.w;
    }
    #pragma unroll
    for (int off = 32; off; off >>= 1) {
        s  += __shfl_xor(s, off);
        s2 += __shfl_xor(s2, off);
    }
    __shared__ double sh[8];
    int wave = threadIdx.x >> 6, lane = threadIdx.x & 63;
    if (lane == 0) { sh[wave * 2] = s; sh[wave * 2 + 1] = s2; }
    __syncthreads();
    if (threadIdx.x == 0) {
        double2 o; o.x = sh[0] + sh[2] + sh[4] + sh[6];
        o.y = sh[1] + sh[3] + sh[5] + sh[7];
        part[p] = o;
    }
}

// bn0 stage 2: combine 16 planes per channel (fixed order), emit affine coeffs
__global__ void bn0_final(const double2* __restrict__ part,
        const float* __restrict__ g, const float* __restrict__ b,
        float* __restrict__ A0, float* __restrict__ B0) {
    int c = threadIdx.x;
    double s = 0.0, s2 = 0.0;
    for (int n = 0; n < NIMG; ++n) {
        double2 v = part[n * 256 + c];
        s += v.x; s2 += v.y;
    }
    double mean = s / (double)NPIX;
    double var  = s2 / (double)NPIX - mean * mean;
    float meanf = (float)mean, varf = (float)var;
    float rstd = (float)(1.0 / sqrt((double)varf + 1e-5));
    float gc = g[c], bc = b[c];
    A0[c] = rstd * gc;
    B0[c] = bc - meanf * rstd * gc;
}

// quantize BN0(x) -> padded NHWC int8 via LDS transpose; one block per (n,h)
__global__ __launch_bounds__(256) void quant0(const float* __restrict__ X,
        const float* __restrict__ A0, const float* __restrict__ B0,
        int8_t* __restrict__ Apad) {
    __shared__ int8_t tile[56 * 260];
    int h = blockIdx.x, n = blockIdx.y;
    int tid = threadIdx.x;
    const float4* src4 = (const float4*)X;
    for (int i = tid; i < 256 * 14; i += 256) {
        int c = i / 14, q = i - c * 14;
        float4 v = src4[((size_t)(n * 256 + c) * HW + h * 56) / 4 + q];
        float ac = A0[c], bc = B0[c];
        float vv[4] = {v.x, v.y, v.z, v.w};
        #pragma unroll
        for (int j = 0; j < 4; ++j) {
            float y = fmaf(vv[j], ac, bc);
            y = fminf(fmaxf(y, 0.f), 1.f);
            tile[(q * 4 + j) * 260 + c] = (int8_t)(int)rintf(y * 15.f);
        }
    }
    __syncthreads();
    unsigned* dst = (unsigned*)(Apad + (((size_t)n * PADH + h + 1) * PADH + 1) * 256);
    for (int i = tid; i < 56 * 64; i += 256) {
        int w = i >> 6, c4 = (i & 63) << 2;
        dst[w * 64 + (c4 >> 2)] = *(const unsigned*)&tile[w * 260 + c4];
    }
}

// both weight tensors' absmax in one launch
__global__ __launch_bounds__(256) void wmax2(const float* __restrict__ W0,
        const float* __restrict__ W1, unsigned* __restrict__ out) {
    const float* Wt = blockIdx.y ? W1 : W0;
    __shared__ float sh[256];
    float m = 0.f;
    for (int i = blockIdx.x * 256 + threadIdx.x; i < WELEMS; i += gridDim.x * 256)
        m = fmaxf(m, fabsf(Wt[i]));
    sh[threadIdx.x] = m; __syncthreads();
    for (int o = 128; o > 0; o >>= 1) {
        if (threadIdx.x < o) sh[threadIdx.x] = fmaxf(sh[threadIdx.x], sh[threadIdx.x + o]);
        __syncthreads();
    }
    if (threadIdx.x == 0) atomicMax(&out[blockIdx.y], __float_as_uint(sh[0]));
}

// quantize both weight tensors into per-lane MFMA fragment layout
// K channel-split: kp = (ci>>7)*1152 + tap*128 + (ci&127)
// Wpack[kt][cot][lane][16]; lane = (kp%32/16)*32 + (o%32); byte j = kp%16
__global__ __launch_bounds__(256) void wpack2(const float* __restrict__ W0,
        const float* __restrict__ W1, const unsigned* __restrict__ maxwBits,
        int8_t* __restrict__ D0, int8_t* __restrict__ D1, float* __restrict__ scales) {
    const float* Wt = blockIdx.y ? W1 : W0;
    int8_t* dst = blockIdx.y ? D1 : D0;
    float maxw = tanhf(__uint_as_float(maxwBits[blockIdx.y]));
    if (blockIdx.x == 0 && threadIdx.x == 0) scales[blockIdx.y] = maxw / 225.f;
    float twoM = 2.f * maxw;
    for (int e = blockIdx.x * 256 + threadIdx.x; e < WELEMS; e += gridDim.x * 256) {
        int o = e / 2304, rem = e % 2304;
        int ci = rem / 9, tap = rem % 9;
        float t = tanhf(Wt[e]);
        float wn = t / twoM + 0.5f;
        int r = (int)rintf(wn * 15.f);
        int q = 2 * r - 15;
        int kp = (ci >> 7) * 1152 + tap * 128 + (ci & 127);
        int kt = kp >> 5, k5 = kp & 31;
        int lane = ((k5 >> 4) << 5) | (o & 31);
        int j = k5 & 15;
        dst[((((size_t)kt * NCOT + (o >> 5)) * 64 + lane) << 4) | j] = (int8_t)q;
    }
}

__device__ __constant__ int moff32_c[4] = {0, 1024, 1792, 2816};

// Tiled implicit-GEMM conv. Block: 1024 thr (16 waves) = 2 rows x 4 images x 128 couts.
// b = rp*8 + ch*4 + ng  ->  b%8 picks the XCD and fixes the cout-half per XCD
// (288 KB weight working set stays L2-resident per XCD).
// Weights: cooperative LDS ring, 2 slots x 16KB, one 4-kt phase (= one 3x3 tap)
// staged ahead via one gll16/thread/phase, vmcnt(1); acts: LDS per 128-ch half.
// Wave (pxg 0..7, cogg 0..1) = 2 px-tiles x 2 cot-tiles, acc 64 AGPR.
template<int CONV1>
__global__ __launch_bounds__(1024, 4) void conv_mfma(const int8_t* __restrict__ A,
        const v4i* __restrict__ Wp, int* __restrict__ Cout,
        unsigned long long* __restrict__ sums,
        const float* __restrict__ scale1p, const float* __restrict__ Xin,
        float* __restrict__ Out) {
    __shared__ v4i actT[8 * 931];         // 119.2 KB: [hh 16ch-granule][img*4+row][58 px]
    __shared__ v4i wring[2][1024];        // 2 x 16 KB: [slot][kk*4+cotl][lane]
    int tid = threadIdx.x;
    int lane = tid & 63, wave = tid >> 6;
    int l31 = lane & 31, half = lane >> 5;
    int pxg = wave & 7, cogg = wave >> 3;
    int b = blockIdx.x;
    int rp = b >> 3, ch = (b >> 2) & 1, ng = b & 3;
    int y0 = rp * 2;

    float s1 = 0.f;
    if (CONV1) s1 = *scale1p;

    // per-lane act pixel indices for the wave's 2 px-tiles (tiles span 4 images)
    int pidx0, pidx1;
    {
        int tgl0 = pxg * 2, tgl1 = tgl0 + 1;
        int s0 = (tgl0 & 3) * 32 + l31, s1x = (tgl1 & 3) * 32 + l31;
        int c0 = s0 & 63, c1 = s1x & 63;
        pidx0 = ((tgl0 >> 2) * 4 + (s0 >> 6) + 1) * 58 + (c0 < 56 ? c0 : 55) + 1;
        pidx1 = ((tgl1 >> 2) * 4 + (s1x >> 6) + 1) * 58 + (c1 < 56 ? c1 : 55) + 1;
    }

    const char* wgb = (const char*)Wp;
    const int8_t* abase = A + (((size_t)ng * 4 * PADH + y0) * PADH) * 256;
    int wktl = tid >> 8;                  // this thread's kt-within-phase
    int woff = (tid & 255) * 16;          // byte offset within the 4KB kt chunk

    v16i acc[2][2] = {};

    #pragma unroll 1
    for (int h = 0; h < 2; ++h) {
        if (h == 0) {
            // stage phase 0 weights into slot 0
            gll16(wgb + (size_t)wktl * 8192 + ch * 4096 + woff,
                  (char*)&wring[0][0] + wktl * 4096 + woff);
        } // h==1: phase 9 already staged by h=0's last loop iteration
        // stage this half's acts: 4 img x 4 padded rows x 58 px x 128 ch
        for (int i = tid; i < 7424; i += 1024) {
            int hh = i & 7, rem = i >> 3;
            int px = rem % 58, ir = rem / 58;       // ir = img*4 + row
            actT[hh * 931 + ir * 58 + px] =
                *(const v4i*)(abase + (((size_t)(ir >> 2) * PADH + (ir & 3)) * PADH + px) * 256
                              + h * 128 + hh * 16);
        }
        __syncthreads();                  // acts + pending weight stage drained

        #pragma unroll 1
        for (int phl = 0; phl < 9; ++phl) {
            int ph = h * 9 + phl;
            int phn = ph + 1 > 17 ? 17 : ph + 1;
            gll16(wgb + (size_t)((phn / 9) * 36 + (phn % 9) * 4 + wktl) * 8192 + ch * 4096 + woff,
                  (char*)&wring[(ph + 1) & 1][0] + wktl * 4096 + woff);
            asm volatile("s_waitcnt vmcnt(1)" ::: "memory");
            __builtin_amdgcn_s_barrier();
            __builtin_amdgcn_sched_barrier(0);
            const v4i* wr = &wring[ph & 1][0];
            int doff = (phl / 3) * 58 + (phl % 3) - 59;
            #pragma unroll
            for (int kk = 0; kk < 4; ++kk) {
                v4i wf0 = wr[(kk * 4 + cogg * 2) * 64 + lane];
                v4i wf1 = wr[(kk * 4 + cogg * 2 + 1) * 64 + lane];
                int hb = (kk * 2 + half) * 931 + doff;
                v4i af0 = actT[hb + pidx0];
                v4i af1 = actT[hb + pidx1];
                if (CONV1) {
                    acc[0][0] = __builtin_amdgcn_mfma_i32_32x32x32_i8(wf0, af0, acc[0][0], 0, 0, 0);
                    acc[0][1] = __builtin_amdgcn_mfma_i32_32x32x32_i8(wf1, af0, acc[0][1], 0, 0, 0);
                    acc[1][0] = __builtin_amdgcn_mfma_i32_32x32x32_i8(wf0, af1, acc[1][0], 0, 0, 0);
                    acc[1][1] = __builtin_amdgcn_mfma_i32_32x32x32_i8(wf1, af1, acc[1][1], 0, 0, 0);
                } else {
                    acc[0][0] = __builtin_amdgcn_mfma_i32_32x32x32_i8(af0, wf0, acc[0][0], 0, 0, 0);
                    acc[0][1] = __builtin_amdgcn_mfma_i32_32x32x32_i8(af0, wf1, acc[0][1], 0, 0, 0);
                    acc[1][0] = __builtin_amdgcn_mfma_i32_32x32x32_i8(af1, wf0, acc[1][0], 0, 0, 0);
                    acc[1][1] = __builtin_amdgcn_mfma_i32_32x32x32_i8(af1, wf1, acc[1][1], 0, 0, 0);
                }
            }
            __builtin_amdgcn_s_barrier();  // reads retired before next overwrite
        }
    }
    asm volatile("s_waitcnt vmcnt(0)" ::: "memory");  // drain tail redundant stage

    if (!CONV1) {
        int base = b * 57344;
        #pragma unroll
        for (int c = 0; c < 2; ++c) {
            int cotl = cogg * 2 + c;
            long long ssum = 0, ssq = 0;
            #pragma unroll
            for (int p = 0; p < 2; ++p) {
                int tgl = pxg * 2 + p;
                int img = tgl >> 2, m = tgl & 3;
                int rc = (m & 1) ? 12 : 16;
                int tb = base + (img * 4 + cotl) * 3584 + moff32_c[m];
                v16i a = acc[p][c];
                #pragma unroll
                for (int r = 0; r < 16; ++r) {
                    if (r < rc) {
                        __builtin_nontemporal_store(a[r], &Cout[tb + r * 64 + lane]);
                        ssum += a[r];
                        ssq  += (long long)a[r] * a[r];
                    }
                }
            }
            ssum += __shfl_xor(ssum, 32);
            ssq  += __shfl_xor(ssq, 32);
            if (half == 0) {
                int co = ch * 128 + cotl * 32 + l31;
                atomicAdd(&sums[co], (unsigned long long)ssum);
                atomicAdd(&sums[256 + co], (unsigned long long)ssq);
            }
        }
    } else {
        #pragma unroll
        for (int p = 0; p < 2; ++p) {
            int tgl = pxg * 2 + p;
            int img = tgl >> 2;
            int s = (tgl & 3) * 32 + l31;
            int rr = s >> 6, col = s & 63;
            if (col < 56) {
                size_t boff = (size_t)(ng * 4 + img) * NCH * HW + (size_t)(y0 + rr) * 56 + col;
                #pragma unroll
                for (int c = 0; c < 2; ++c) {
                    int cotl = cogg * 2 + c;
                    v16i a = acc[p][c];
                    #pragma unroll
                    for (int r = 0; r < 16; ++r) {
                        int co = ch * 128 + cotl * 32 + (r & 3) + ((r >> 2) << 3) + (half << 2);
                        size_t off = boff + (size_t)co * HW;
                        float xv = __builtin_nontemporal_load(&Xin[off]);
                        __builtin_nontemporal_store(fmaf(s1, (float)a[r], xv), &Out[off]);
                    }
                }
            }
        }
    }
}

__global__ void bn1_finalize(const unsigned long long* __restrict__ sums,
        const float* __restrict__ g, const float* __restrict__ b,
        const float* __restrict__ scale0p, float* __restrict__ A1, float* __restrict__ B1) {
    int c = threadIdx.x;
    double sc0 = (double)*scale0p;
    double S  = (double)(long long)sums[c];
    double S2 = (double)(long long)sums[256 + c];
    double meanS = S / (double)NPIX;
    double varS  = S2 / (double)NPIX - meanS * meanS;
    float meanf = (float)(sc0 * meanS);
    float varf  = (float)(sc0 * sc0 * varS);
    float rstd = (float)(1.0 / sqrt((double)varf + 1e-5));
    float gc = g[c], bc = b[c];
    A1[c] = (float)(sc0 * (double)rstd * (double)gc);
    B1[c] = bc - meanf * rstd * gc;
}

// requantize conv0 tile-layout output -> padded NHWC int8. One block per (n, rp).
__global__ __launch_bounds__(256) void quant1(const int* __restrict__ Cin,
        const float* __restrict__ A1, const float* __restrict__ B1,
        int8_t* __restrict__ Apad) {
    __shared__ int8_t tile[112 * 260];
    __shared__ float a1s[256], b1s[256];
    int blk = blockIdx.x;                 // n*28 + rp
    int n = blk / 28, rp = blk % 28;
    int t = threadIdx.x;
    a1s[t] = A1[t]; b1s[t] = B1[t];
    __syncthreads();
    int ng = n >> 2, img = n & 3;
    #pragma unroll
    for (int ch = 0; ch < 2; ++ch) {
        int cb = (rp * 8 + ch * 4 + ng) * 57344 + img * 4 * 3584;
        for (int i = t; i < 14336; i += 256) {
            int cotl = i / 3584, idx = i - cotl * 3584;
            int m, loc;
            if (idx < 1024)      { m = 0; loc = idx; }
            else if (idx < 1792) { m = 1; loc = idx - 1024; }
            else if (idx < 2816) { m = 2; loc = idx - 1792; }
            else                 { m = 3; loc = idx - 2816; }
            int r = loc >> 6, lane = loc & 63;
            int co = ch * 128 + cotl * 32 + (lane & 31);
            int ps = (r & 3) + ((r >> 2) << 3) + ((lane >> 5) << 2);
            int s = m * 32 + ps;
            int px = (s >> 6) * 56 + (s & 63);
            float y = fmaf((float)Cin[cb + i], a1s[co], b1s[co]);
            y = fminf(fmaxf(y, 0.f), 1.f);
            tile[px * 260 + co] = (int8_t)(int)rintf(y * 15.f);
        }
    }
    __syncthreads();
    for (int i = t; i < 112 * 64; i += 256) {
        int px = i >> 6, w = i & 63;
        int y = rp * 2 + (px >= 56 ? 1 : 0);
        int x = px - (px >= 56 ? 56 : 0);
        size_t dst = (((size_t)n * PADH + y + 1) * PADH + x + 1) * 256 + w * 4;
        *(unsigned*)&Apad[dst] = *(const unsigned*)&tile[px * 260 + w * 4];
    }
}

extern "C" void kernel_launch(void* const* d_in, const int* in_sizes, int n_in,
                              void* d_out, int out_size, void* d_ws, size_t ws_size,
                              hipStream_t stream) {
    const float* x  = (const float*)d_in[0];
    const float* g0 = (const float*)d_in[1];
    const float* b0 = (const float*)d_in[2];
    const float* w0 = (const float*)d_in[3];
    const float* g1 = (const float*)d_in[4];
    const float* b1 = (const float*)d_in[5];
    const float* w1 = (const float*)d_in[6];
    float* out = (float*)d_out;

    char* ws = (char*)d_ws;
    int8_t* a0 = (int8_t*)(ws + A0_OFF);
    v4i* wp0 = (v4i*)(ws + WP0_OFF);
    v4i* wp1 = (v4i*)(ws + WP1_OFF);
    float* coef = (float*)(ws + COEF_OFF);
    float* A0c = coef;       float* B0c = coef + 256;
    float* A1c = coef + 512; float* B1c = coef + 768;
    float* scales = coef + 1024;
    unsigned* maxw = (unsigned*)(ws + MAXW_OFF);
    unsigned long long* sums = (unsigned long long*)(ws + SUM1_OFF);
    double2* part = (double2*)(ws + PART_OFF);

    int* c0 = (int*)d_out;   // conv0 tile-layout int32 lives in d_out until conv1 overwrites

    hipMemsetAsync(a0, 0, A0_BYTES, stream);
    bn0_part<<<4096, 256, 0, stream>>>(x, part, maxw, sums);
    bn0_final<<<1, 256, 0, stream>>>(part, g0, b0, A0c, B0c);
    quant0<<<dim3(56, 16), 256, 0, stream>>>(x, A0c, B0c, a0);
    wmax2<<<dim3(256, 2), 256, 0, stream>>>(w0, w1, maxw);
    wpack2<<<dim3(128, 2), 256, 0, stream>>>(w0, w1, maxw, (int8_t*)wp0, (int8_t*)wp1, scales);
    conv_mfma<0><<<224, 1024, 0, stream>>>(a0, wp0, c0, sums, nullptr, nullptr, nullptr);
    bn1_finalize<<<1, 256, 0, stream>>>(sums, g1, b1, scales, A1c, B1c);
    quant1<<<448, 256, 0, stream>>>(c0, A1c, B1c, a0);
    conv_mfma<1><<<224, 1024, 0, stream>>>(a0, wp1, nullptr, nullptr, scales + 1, x, out);
}

// Round 10
// 181.971 us; speedup vs baseline: 1.3131x; 1.3131x over previous
//
#include <hip/hip_runtime.h>
#include <stdint.h>
#include <math.h>

typedef int v4i  __attribute__((ext_vector_type(4)));
typedef int v16i __attribute__((ext_vector_type(16)));

#define NIMG 16
#define NCH  256
#define HW   3136          // 56*56
#define NPIX 50176         // 16*3136
#define PADH 58
#define NKT  72            // 2304/32
#define NCOT 8             // 256/32
#define WELEMS 589824      // 256*256*3*3

// workspace layout (bytes)
#define A0_OFF   0
#define A0_BYTES (16*58*58*256)          // padded NHWC int8 acts
#define WP0_OFF  (A0_OFF + A0_BYTES)
#define WP_BYTES (NKT*NCOT*64*16)        // 589,824 packed weight frags
#define WP1_OFF  (WP0_OFF + WP_BYTES)
#define COEF_OFF (WP1_OFF + WP_BYTES)    // floats A0[256] B0[256] A1[256] B1[256] scale0 scale1
#define MAXW_OFF (COEF_OFF + 4352)       // 2 x u32
#define SUM1_OFF (MAXW_OFF + 32)         // 512 x u64
#define PART_OFF (SUM1_OFF + 4096)       // 4096 x double2 (bn0 per-plane partials)

// bn0 stage 1: per-(n,c)-plane sum/sumsq in double, one block per plane.
// block 0 also zero-inits maxw/sums (consumed later in stream order).
__global__ __launch_bounds__(256) void bn0_part(const float* __restrict__ X,
        double2* __restrict__ part, unsigned* __restrict__ maxw,
        unsigned long long* __restrict__ sums) {
    if (blockIdx.x == 0) {
        int t = threadIdx.x;
        if (t < 2) maxw[t] = 0u;
        for (int i = t; i < 512; i += 256) sums[i] = 0ull;
    }
    int p = blockIdx.x;                    // n*256 + c
    const float4* src = (const float4*)(X + (size_t)p * HW);
    double s = 0.0, s2 = 0.0;
    for (int i = threadIdx.x; i < HW / 4; i += 256) {
        float4 v = src[i];
        s  += (double)v.x + (double)v.y + (double)v.z + (double)v.w;
        s2 += (double)v.x * (double)v.x + (double)v.y * (double)v.y
            + (double)v.z * (double)v.z + (double)v.w * (double)v.w;
    }
    #pragma unroll
    for (int off = 32; off; off >>= 1) {
        s  += __shfl_xor(s, off);
        s2 += __shfl_xor(s2, off);
    }
    __shared__ double sh[8];
    int wave = threadIdx.x >> 6, lane = threadIdx.x & 63;
    if (lane == 0) { sh[wave * 2] = s; sh[wave * 2 + 1] = s2; }
    __syncthreads();
    if (threadIdx.x == 0) {
        double2 o; o.x = sh[0] + sh[2] + sh[4] + sh[6];
        o.y = sh[1] + sh[3] + sh[5] + sh[7];
        part[p] = o;
    }
}

// bn0 stage 2: combine 16 planes per channel (fixed order), emit affine coeffs
__global__ void bn0_final(const double2* __restrict__ part,
        const float* __restrict__ g, const float* __restrict__ b,
        float* __restrict__ A0, float* __restrict__ B0) {
    int c = threadIdx.x;
    double s = 0.0, s2 = 0.0;
    for (int n = 0; n < NIMG; ++n) {
        double2 v = part[n * 256 + c];
        s += v.x; s2 += v.y;
    }
    double mean = s / (double)NPIX;
    double var  = s2 / (double)NPIX - mean * mean;
    float meanf = (float)mean, varf = (float)var;
    float rstd = (float)(1.0 / sqrt((double)varf + 1e-5));
    float gc = g[c], bc = b[c];
    A0[c] = rstd * gc;
    B0[c] = bc - meanf * rstd * gc;
}

// quantize BN0(x) -> padded NHWC int8 via LDS transpose; one block per (n,h)
__global__ __launch_bounds__(256) void quant0(const float* __restrict__ X,
        const float* __restrict__ A0, const float* __restrict__ B0,
        int8_t* __restrict__ Apad) {
    __shared__ int8_t tile[56 * 260];     // stride 260: conflict-free byte columns
    int h = blockIdx.x, n = blockIdx.y;
    int tid = threadIdx.x;
    const float4* src4 = (const float4*)X;
    for (int i = tid; i < 256 * 14; i += 256) {
        int c = i / 14, q = i - c * 14;
        float4 v = src4[((size_t)(n * 256 + c) * HW + h * 56) / 4 + q];
        float ac = A0[c], bc = B0[c];
        float vv[4] = {v.x, v.y, v.z, v.w};
        #pragma unroll
        for (int j = 0; j < 4; ++j) {
            float y = fmaf(vv[j], ac, bc);
            y = fminf(fmaxf(y, 0.f), 1.f);
            tile[(q * 4 + j) * 260 + c] = (int8_t)(int)rintf(y * 15.f);
        }
    }
    __syncthreads();
    unsigned* dst = (unsigned*)(Apad + (((size_t)n * PADH + h + 1) * PADH + 1) * 256);
    for (int i = tid; i < 56 * 64; i += 256) {
        int w = i >> 6, c4 = (i & 63) << 2;
        dst[w * 64 + (c4 >> 2)] = *(const unsigned*)&tile[w * 260 + c4];
    }
}

// both weight tensors' absmax in one launch (blockIdx.y selects tensor)
__global__ __launch_bounds__(256) void wmax2(const float* __restrict__ W0,
        const float* __restrict__ W1, unsigned* __restrict__ out) {
    const float* Wt = blockIdx.y ? W1 : W0;
    __shared__ float sh[256];
    float m = 0.f;
    for (int i = blockIdx.x * 256 + threadIdx.x; i < WELEMS; i += gridDim.x * 256)
        m = fmaxf(m, fabsf(Wt[i]));
    sh[threadIdx.x] = m; __syncthreads();
    for (int o = 128; o > 0; o >>= 1) {
        if (threadIdx.x < o) sh[threadIdx.x] = fmaxf(sh[threadIdx.x], sh[threadIdx.x + o]);
        __syncthreads();
    }
    if (threadIdx.x == 0) atomicMax(&out[blockIdx.y], __float_as_uint(sh[0]));
}

// quantize both weight tensors into per-lane MFMA fragment layout (blockIdx.y selects)
// Wpack[kt][cot][lane][16] ; k = tap*256 + ci ; lane = (k%32/16)*32 + (o%32) ; byte j = k%16
__global__ __launch_bounds__(256) void wpack2(const float* __restrict__ W0,
        const float* __restrict__ W1, const unsigned* __restrict__ maxwBits,
        int8_t* __restrict__ D0, int8_t* __restrict__ D1, float* __restrict__ scales) {
    const float* Wt = blockIdx.y ? W1 : W0;
    int8_t* dst = blockIdx.y ? D1 : D0;
    float maxw = tanhf(__uint_as_float(maxwBits[blockIdx.y]));
    if (blockIdx.x == 0 && threadIdx.x == 0) scales[blockIdx.y] = maxw / 225.f;
    float twoM = 2.f * maxw;
    for (int e = blockIdx.x * 256 + threadIdx.x; e < WELEMS; e += gridDim.x * 256) {
        int o = e / 2304, rem = e % 2304;
        int ci = rem / 9, tap = rem % 9;
        float t = tanhf(Wt[e]);
        float wn = t / twoM + 0.5f;
        int r = (int)rintf(wn * 15.f);
        int q = 2 * r - 15;
        int k = tap * 256 + ci;
        int kt = k >> 5, k5 = k & 31;
        int lane = ((k5 >> 4) << 5) | (o & 31);
        int j = k5 & 15;
        dst[((((size_t)kt * NCOT + (o >> 5)) * 64 + lane) << 4) | j] = (int8_t)q;
    }
}

typedef __attribute__((address_space(1))) const unsigned int gu32;
typedef __attribute__((address_space(3))) unsigned int lu32;
__device__ __forceinline__ void gll16(const void* g, void* l) {
    __builtin_amdgcn_global_load_lds((gu32*)g, (lu32*)l, 16, 0, 0);
}

// wave w stages its own two 1KB weight chunks (cout-tiles c0, c1) of K-step ktn
__device__ __forceinline__ void stageW(const char* wgb, char* ldsbuf,
        int ktn, int c0, int c1, int lane) {
    const char* src = wgb + (size_t)ktn * 8192;
    gll16(src + c0 * 1024 + lane * 16, ldsbuf + c0 * 1024 + lane * 16);
    gll16(src + c1 * 1024 + lane * 16, ldsbuf + c1 * 1024 + lane * 16);
}

// Tiled implicit-GEMM conv. Block: 4 waves, 2 image rows x 256 couts (r4 base).
// conv0 epilogue: int16 Cout ((s+8)>>4 exact fit, +-8 error) + fused exact bn1
// stats; plain stores (L3 keeps Cout for quant1). conv1: plain Xin loads (L3-hot).
template<int CONV1>
__global__ __launch_bounds__(256, 2) void conv_mfma(const int8_t* __restrict__ A,
        const v4i* __restrict__ Wp, short* __restrict__ Cout,
        unsigned long long* __restrict__ sums,
        const float* __restrict__ scale1p, const float* __restrict__ Xin,
        float* __restrict__ Out) {
    __shared__ v4i actT[16 * 233];        // 59.6 KB, read-only after prologue
    __shared__ v4i wbuf[2][512];          // 2 x 8 KB, per-wave chunk ownership
    int tid = threadIdx.x;
    int lane = tid & 63, wave = tid >> 6;
    int rp = blockIdx.x, n = blockIdx.y;
    int y0 = rp * 2;
    int l31 = lane & 31, half = lane >> 5;

    float s1 = 0.f;
    if (CONV1) s1 = *scale1p;

    // ---- act staging: padded rows y0..y0+3, 58 cols, 256 ch -> transposed LDS
    const int8_t* asrc = A + (((size_t)n * PADH + y0) * PADH) * 256;
    for (int i = tid; i < 4 * 58 * 16; i += 256) {
        int rr = i / (58 * 16);
        int rem = i - rr * (58 * 16);
        int px = rem >> 4, hh = rem & 15;
        v4i v = *(const v4i*)(asrc + ((size_t)rr * PADH + px) * 256 + hh * 16);
        actT[hh * 233 + rr * 58 + px] = v;
    }
    __syncthreads();   // actT read-only from here

    int c0 = wave, c1 = wave + 4;
    const char* wgb = (const char*)Wp;
    stageW(wgb, (char*)&wbuf[0][0], 0, c0, c1, lane);   // W[0], own chunks

    int pidx[4];
    #pragma unroll
    for (int m = 0; m < 4; ++m) {
        int s = m * 32 + l31;
        int rr = s >> 6, col = s & 63;
        int xx = col < 56 ? col : 55;
        pidx[m] = (rr + 1) * 58 + xx + 1;
    }

    v16i acc[8] = {};

    int kt = 0;
    #pragma unroll 1
    for (int dyi = 0; dyi < 3; ++dyi) {
        #pragma unroll
        for (int dxi = 0; dxi < 3; ++dxi) {
            int doff = dyi * 58 + dxi - 59;
            #pragma unroll
            for (int kk = 0; kk < 8; ++kk) {
                int ktn = kt + 1; if (ktn > 71) ktn = 71;
                stageW(wgb, (char*)&wbuf[ktn & 1][0], ktn, c0, c1, lane);
                asm volatile("s_waitcnt vmcnt(2)" ::: "memory");
                const v4i* wb = &wbuf[kt & 1][0];
                int hb = (kk * 2 + half) * 233 + doff;
                v4i wf0 = wb[c0 * 64 + lane];
                v4i wf1 = wb[c1 * 64 + lane];
                v4i af0 = actT[hb + pidx[0]];
                v4i af1 = actT[hb + pidx[1]];
                v4i af2 = actT[hb + pidx[2]];
                v4i af3 = actT[hb + pidx[3]];
                if (CONV1) {
                    acc[0] = __builtin_amdgcn_mfma_i32_32x32x32_i8(wf0, af0, acc[0], 0, 0, 0);
                    acc[1] = __builtin_amdgcn_mfma_i32_32x32x32_i8(wf0, af1, acc[1], 0, 0, 0);
                    acc[2] = __builtin_amdgcn_mfma_i32_32x32x32_i8(wf0, af2, acc[2], 0, 0, 0);
                    acc[3] = __builtin_amdgcn_mfma_i32_32x32x32_i8(wf0, af3, acc[3], 0, 0, 0);
                    acc[4] = __builtin_amdgcn_mfma_i32_32x32x32_i8(wf1, af0, acc[4], 0, 0, 0);
                    acc[5] = __builtin_amdgcn_mfma_i32_32x32x32_i8(wf1, af1, acc[5], 0, 0, 0);
                    acc[6] = __builtin_amdgcn_mfma_i32_32x32x32_i8(wf1, af2, acc[6], 0, 0, 0);
                    acc[7] = __builtin_amdgcn_mfma_i32_32x32x32_i8(wf1, af3, acc[7], 0, 0, 0);
                } else {
                    acc[0] = __builtin_amdgcn_mfma_i32_32x32x32_i8(af0, wf0, acc[0], 0, 0, 0);
                    acc[1] = __builtin_amdgcn_mfma_i32_32x32x32_i8(af1, wf0, acc[1], 0, 0, 0);
                    acc[2] = __builtin_amdgcn_mfma_i32_32x32x32_i8(af2, wf0, acc[2], 0, 0, 0);
                    acc[3] = __builtin_amdgcn_mfma_i32_32x32x32_i8(af3, wf0, acc[3], 0, 0, 0);
                    acc[4] = __builtin_amdgcn_mfma_i32_32x32x32_i8(af0, wf1, acc[4], 0, 0, 0);
                    acc[5] = __builtin_amdgcn_mfma_i32_32x32x32_i8(af1, wf1, acc[5], 0, 0, 0);
                    acc[6] = __builtin_amdgcn_mfma_i32_32x32x32_i8(af2, wf1, acc[6], 0, 0, 0);
                    acc[7] = __builtin_amdgcn_mfma_i32_32x32x32_i8(af3, wf1, acc[7], 0, 0, 0);
                }
                ++kt;
            }
        }
    }
    asm volatile("s_waitcnt vmcnt(0)" ::: "memory");

    if (!CONV1) {
        int pbase = n * HW + y0 * 56;
        #pragma unroll
        for (int ci = 0; ci < 2; ++ci) {
            int co = (wave + ci * 4) * 32 + l31;
            long long ssum = 0, ssq = 0;
            #pragma unroll
            for (int m = 0; m < 4; ++m) {
                v16i a = acc[ci * 4 + m];
                #pragma unroll
                for (int r = 0; r < 16; ++r) {
                    int prow = (r & 3) + ((r >> 2) << 3) + (half << 2);
                    int s = m * 32 + prow;
                    int rr = s >> 6, col = s & 63;
                    if (col < 56) {
                        // int16 compact: (s+8)>>4 fits +-32400, unbiased +-8 error
                        Cout[(size_t)(pbase + rr * 56 + col) * 256 + co] =
                            (short)((a[r] + 8) >> 4);
                        ssum += a[r];                       // exact stats from raw acc
                        ssq  += (long long)a[r] * a[r];
                    }
                }
            }
            ssum += __shfl_xor(ssum, 32);
            ssq  += __shfl_xor(ssq, 32);
            if (half == 0) {
                atomicAdd(&sums[co], (unsigned long long)ssum);
                atomicAdd(&sums[256 + co], (unsigned long long)ssq);
            }
        }
    } else {
        #pragma unroll
        for (int m = 0; m < 4; ++m) {
            int s = m * 32 + l31;
            int rr = s >> 6, col = s & 63;
            if (col < 56) {
                size_t boff = (size_t)n * NCH * HW + (size_t)(y0 + rr) * 56 + col;
                #pragma unroll
                for (int ci = 0; ci < 2; ++ci) {
                    v16i a = acc[ci * 4 + m];
                    #pragma unroll
                    for (int r = 0; r < 16; ++r) {
                        int prow = (r & 3) + ((r >> 2) << 3) + (half << 2);
                        int co = (wave + ci * 4) * 32 + prow;
                        size_t off = boff + (size_t)co * HW;
                        Out[off] = fmaf(s1, (float)a[r], Xin[off]);
                    }
                }
            }
        }
    }
}

__global__ void bn1_finalize(const unsigned long long* __restrict__ sums,
        const float* __restrict__ g, const float* __restrict__ b,
        const float* __restrict__ scale0p, float* __restrict__ A1, float* __restrict__ B1) {
    int c = threadIdx.x;
    double sc0 = (double)*scale0p;
    double S  = (double)(long long)sums[c];
    double S2 = (double)(long long)sums[256 + c];
    double meanS = S / (double)NPIX;
    double varS  = S2 / (double)NPIX - meanS * meanS;
    float meanf = (float)(sc0 * meanS);
    float varf  = (float)(sc0 * sc0 * varS);
    float rstd = (float)(1.0 / sqrt((double)varf + 1e-5));
    float gc = g[c], bc = b[c];
    A1[c] = (float)(sc0 * (double)rstd * (double)gc * 16.0);  // x16: int16 stored (s+8)>>4
    B1[c] = bc - meanf * rstd * gc;
}

// requantize conv0 int16 output -> padded NHWC int8 (reuses act buffer; halo still zero)
__global__ __launch_bounds__(256) void quant1(const short* __restrict__ Cin,
        const float* __restrict__ A1, const float* __restrict__ B1,
        int8_t* __restrict__ A) {
    int idx = blockIdx.x * 256 + threadIdx.x;
    int e4 = idx * 4;
    if (e4 >= NPIX * 256) return;
    int p = e4 >> 8, c4 = e4 & 255;
    int n = p / HW, r2 = p % HW, y = r2 / 56, xx = r2 % 56;
    const short4 v = *(const short4*)(Cin + e4);
    short vv[4] = {v.x, v.y, v.z, v.w};
    unsigned char qq[4];
    #pragma unroll
    for (int j = 0; j < 4; ++j) {
        float y1 = fmaf((float)vv[j], A1[c4 + j], B1[c4 + j]);
        y1 = fminf(fmaxf(y1, 0.f), 1.f);
        qq[j] = (unsigned char)(int)rintf(y1 * 15.f);
    }
    uchar4 q; q.x = qq[0]; q.y = qq[1]; q.z = qq[2]; q.w = qq[3];
    size_t dst = (((size_t)n * PADH + y + 1) * PADH + xx + 1) * 256 + c4;
    *(uchar4*)(A + dst) = q;
}

extern "C" void kernel_launch(void* const* d_in, const int* in_sizes, int n_in,
                              void* d_out, int out_size, void* d_ws, size_t ws_size,
                              hipStream_t stream) {
    const float* x  = (const float*)d_in[0];
    const float* g0 = (const float*)d_in[1];
    const float* b0 = (const float*)d_in[2];
    const float* w0 = (const float*)d_in[3];
    const float* g1 = (const float*)d_in[4];
    const float* b1 = (const float*)d_in[5];
    const float* w1 = (const float*)d_in[6];
    float* out = (float*)d_out;

    char* ws = (char*)d_ws;
    int8_t* a0 = (int8_t*)(ws + A0_OFF);
    v4i* wp0 = (v4i*)(ws + WP0_OFF);
    v4i* wp1 = (v4i*)(ws + WP1_OFF);
    float* coef = (float*)(ws + COEF_OFF);
    float* A0c = coef;       float* B0c = coef + 256;
    float* A1c = coef + 512; float* B1c = coef + 768;
    float* scales = coef + 1024;             // [0]=scale0 [1]=scale1
    unsigned* maxw = (unsigned*)(ws + MAXW_OFF);
    unsigned long long* sums = (unsigned long long*)(ws + SUM1_OFF);
    double2* part = (double2*)(ws + PART_OFF);

    short* c0 = (short*)d_out;   // conv0 int16 sums live in d_out until conv1 overwrites

    hipMemsetAsync(a0, 0, A0_BYTES, stream);
    bn0_part<<<4096, 256, 0, stream>>>(x, part, maxw, sums);
    bn0_final<<<1, 256, 0, stream>>>(part, g0, b0, A0c, B0c);
    quant0<<<dim3(56, 16), 256, 0, stream>>>(x, A0c, B0c, a0);
    wmax2<<<dim3(256, 2), 256, 0, stream>>>(w0, w1, maxw);
    wpack2<<<dim3(128, 2), 256, 0, stream>>>(w0, w1, maxw, (int8_t*)wp0, (int8_t*)wp1, scales);
    conv_mfma<0><<<dim3(28, 16), 256, 0, stream>>>(a0, wp0, c0, sums, nullptr, nullptr, nullptr);
    bn1_finalize<<<1, 256, 0, stream>>>(sums, g1, b1, scales, A1c, B1c);
    quant1<<<12544, 256, 0, stream>>>(c0, A1c, B1c, a0);
    conv_mfma<1><<<dim3(28, 16), 256, 0, stream>>>(a0, wp1, nullptr, nullptr, scales + 1, x, out);
}

// Round 11
// 180.108 us; speedup vs baseline: 1.3267x; 1.0103x over previous
//
#include <hip/hip_runtime.h>
#include <stdint.h>
#include <math.h>

typedef int v4i  __attribute__((ext_vector_type(4)));
typedef int v16i __attribute__((ext_vector_type(16)));

#define NIMG 16
#define NCH  256
#define HW   3136          // 56*56
#define NPIX 50176         // 16*3136
#define PADH 58
#define NKT  72            // 2304/32
#define NCOT 8             // 256/32
#define WELEMS 589824      // 256*256*3*3

// workspace layout (bytes)
#define A0_OFF   0
#define A0_BYTES (16*58*58*256)          // padded NHWC int8 acts
#define WP0_OFF  (A0_OFF + A0_BYTES)
#define WP_BYTES (NKT*NCOT*64*16)        // 589,824 packed weight frags
#define WP1_OFF  (WP0_OFF + WP_BYTES)
#define COEF_OFF (WP1_OFF + WP_BYTES)    // floats A0[256] B0[256] A1[256] B1[256] scale0 scale1
#define MAXW_OFF (COEF_OFF + 4352)       // 2 x u32
#define SUM1_OFF (MAXW_OFF + 32)         // 512 x u64
#define PART_OFF (SUM1_OFF + 4096)       // 4096 x double2 (bn0 per-plane partials)

// bn0 stage 1: per-(n,c)-plane sum/sumsq in double, one block per plane.
__global__ __launch_bounds__(256) void bn0_part(const float* __restrict__ X,
        double2* __restrict__ part, unsigned* __restrict__ maxw,
        unsigned long long* __restrict__ sums) {
    if (blockIdx.x == 0) {
        int t = threadIdx.x;
        if (t < 2) maxw[t] = 0u;
        for (int i = t; i < 512; i += 256) sums[i] = 0ull;
    }
    int p = blockIdx.x;                    // n*256 + c
    const float4* src = (const float4*)(X + (size_t)p * HW);
    double s = 0.0, s2 = 0.0;
    for (int i = threadIdx.x; i < HW / 4; i += 256) {
        float4 v = src[i];
        s  += (double)v.x + (double)v.y + (double)v.z + (double)v.w;
        s2 += (double)v.x * (double)v.x + (double)v.y * (double)v.y
            + (double)v.z * (double)v.z + (double)v.w * (double)v.w;
    }
    #pragma unroll
    for (int off = 32; off; off >>= 1) {
        s  += __shfl_xor(s, off);
        s2 += __shfl_xor(s2, off);
    }
    __shared__ double sh[8];
    int wave = threadIdx.x >> 6, lane = threadIdx.x & 63;
    if (lane == 0) { sh[wave * 2] = s; sh[wave * 2 + 1] = s2; }
    __syncthreads();
    if (threadIdx.x == 0) {
        double2 o; o.x = sh[0] + sh[2] + sh[4] + sh[6];
        o.y = sh[1] + sh[3] + sh[5] + sh[7];
        part[p] = o;
    }
}

// bn0 stage 2: combine 16 planes per channel (fixed order), emit affine coeffs
__global__ void bn0_final(const double2* __restrict__ part,
        const float* __restrict__ g, const float* __restrict__ b,
        float* __restrict__ A0, float* __restrict__ B0) {
    int c = threadIdx.x;
    double s = 0.0, s2 = 0.0;
    for (int n = 0; n < NIMG; ++n) {
        double2 v = part[n * 256 + c];
        s += v.x; s2 += v.y;
    }
    double mean = s / (double)NPIX;
    double var  = s2 / (double)NPIX - mean * mean;
    float meanf = (float)mean, varf = (float)var;
    float rstd = (float)(1.0 / sqrt((double)varf + 1e-5));
    float gc = g[c], bc = b[c];
    A0[c] = rstd * gc;
    B0[c] = bc - meanf * rstd * gc;
}

// quantize BN0(x) -> padded NHWC int8 via LDS transpose; one block per (n,h)
__global__ __launch_bounds__(256) void quant0(const float* __restrict__ X,
        const float* __restrict__ A0, const float* __restrict__ B0,
        int8_t* __restrict__ Apad) {
    __shared__ int8_t tile[56 * 260];     // stride 260: conflict-free byte columns
    int h = blockIdx.x, n = blockIdx.y;
    int tid = threadIdx.x;
    const float4* src4 = (const float4*)X;
    for (int i = tid; i < 256 * 14; i += 256) {
        int c = i / 14, q = i - c * 14;
        float4 v = src4[((size_t)(n * 256 + c) * HW + h * 56) / 4 + q];
        float ac = A0[c], bc = B0[c];
        float vv[4] = {v.x, v.y, v.z, v.w};
        #pragma unroll
        for (int j = 0; j < 4; ++j) {
            float y = fmaf(vv[j], ac, bc);
            y = fminf(fmaxf(y, 0.f), 1.f);
            tile[(q * 4 + j) * 260 + c] = (int8_t)(int)rintf(y * 15.f);
        }
    }
    __syncthreads();
    unsigned* dst = (unsigned*)(Apad + (((size_t)n * PADH + h + 1) * PADH + 1) * 256);
    for (int i = tid; i < 56 * 64; i += 256) {
        int w = i >> 6, c4 = (i & 63) << 2;
        dst[w * 64 + (c4 >> 2)] = *(const unsigned*)&tile[w * 260 + c4];
    }
}

// both weight tensors' absmax in one launch (blockIdx.y selects tensor)
__global__ __launch_bounds__(256) void wmax2(const float* __restrict__ W0,
        const float* __restrict__ W1, unsigned* __restrict__ out) {
    const float* Wt = blockIdx.y ? W1 : W0;
    __shared__ float sh[256];
    float m = 0.f;
    for (int i = blockIdx.x * 256 + threadIdx.x; i < WELEMS; i += gridDim.x * 256)
        m = fmaxf(m, fabsf(Wt[i]));
    sh[threadIdx.x] = m; __syncthreads();
    for (int o = 128; o > 0; o >>= 1) {
        if (threadIdx.x < o) sh[threadIdx.x] = fmaxf(sh[threadIdx.x], sh[threadIdx.x + o]);
        __syncthreads();
    }
    if (threadIdx.x == 0) atomicMax(&out[blockIdx.y], __float_as_uint(sh[0]));
}

// quantize both weight tensors into per-lane MFMA fragment layout (blockIdx.y selects)
// K channel-split: kp = (ci>>7)*1152 + tap*128 + (ci&127)   [proven in R7]
// Wpack[kt][cot][lane][16]; lane = (kp%32/16)*32 + (o%32); byte j = kp%16
__global__ __launch_bounds__(256) void wpack2(const float* __restrict__ W0,
        const float* __restrict__ W1, const unsigned* __restrict__ maxwBits,
        int8_t* __restrict__ D0, int8_t* __restrict__ D1, float* __restrict__ scales) {
    const float* Wt = blockIdx.y ? W1 : W0;
    int8_t* dst = blockIdx.y ? D1 : D0;
    float maxw = tanhf(__uint_as_float(maxwBits[blockIdx.y]));
    if (blockIdx.x == 0 && threadIdx.x == 0) scales[blockIdx.y] = maxw / 225.f;
    float twoM = 2.f * maxw;
    for (int e = blockIdx.x * 256 + threadIdx.x; e < WELEMS; e += gridDim.x * 256) {
        int o = e / 2304, rem = e % 2304;
        int ci = rem / 9, tap = rem % 9;
        float t = tanhf(Wt[e]);
        float wn = t / twoM + 0.5f;
        int r = (int)rintf(wn * 15.f);
        int q = 2 * r - 15;
        int kp = (ci >> 7) * 1152 + tap * 128 + (ci & 127);
        int kt = kp >> 5, k5 = kp & 31;
        int lane = ((k5 >> 4) << 5) | (o & 31);
        int j = k5 & 15;
        dst[((((size_t)kt * NCOT + (o >> 5)) * 64 + lane) << 4) | j] = (int8_t)q;
    }
}

typedef __attribute__((address_space(1))) const unsigned int gu32;
typedef __attribute__((address_space(3))) unsigned int lu32;
__device__ __forceinline__ void gll16(const void* g, void* l) {
    __builtin_amdgcn_global_load_lds((gu32*)g, (lu32*)l, 16, 0, 0);
}

// Tiled implicit-GEMM conv, BK=64 double-step K-loop.
// Block: 4 waves, 2 image rows x 256 couts; acts channel-split (29.8 KB/half);
// weight ring 2 slots x 16 KB (slot = 2 kt x 8 cot), per-wave chunk ownership,
// counted vmcnt(4) (never 0 in-loop), no K-loop barriers, setprio around MFMA.
// conv0 epilogue: int16 Cout ((s+8)>>4) + fused exact bn1 stats.
template<int CONV1>
__global__ __launch_bounds__(256, 2) void conv_mfma(const int8_t* __restrict__ A,
        const v4i* __restrict__ Wp, short* __restrict__ Cout,
        unsigned long long* __restrict__ sums,
        const float* __restrict__ scale1p, const float* __restrict__ Xin,
        float* __restrict__ Out) {
    __shared__ v4i actT[8 * 233];         // 29.8 KB: one 128-ch half, transposed
    __shared__ v4i wring[2][1024];        // 2 x 16 KB: [slot][(j*8+cot)*64+lane]
    int tid = threadIdx.x;
    int lane = tid & 63, wave = tid >> 6;
    int rp = blockIdx.x, n = blockIdx.y;
    int y0 = rp * 2;
    int l31 = lane & 31, half = lane >> 5;

    float s1 = 0.f;
    if (CONV1) s1 = *scale1p;

    int c0 = wave, c1 = wave + 4;
    const char* wgb = (const char*)Wp;
    const int8_t* asrc = A + (((size_t)n * PADH + y0) * PADH) * 256;

    int pidx[4];
    #pragma unroll
    for (int m = 0; m < 4; ++m) {
        int s = m * 32 + l31;
        int rr = s >> 6, col = s & 63;
        int xx = col < 56 ? col : 55;
        pidx[m] = (rr + 1) * 58 + xx + 1;
    }

    v16i acc[8] = {};

    #pragma unroll 1
    for (int h = 0; h < 2; ++h) {
        if (h) __syncthreads();           // all reads of actT/wring slot done
        // stage this half's acts: 4 padded rows x 58 px x 128 ch
        for (int i = tid; i < 4 * 58 * 8; i += 256) {
            int rr = i / (58 * 8);
            int rem = i - rr * (58 * 8);
            int px = rem >> 3, hh = rem & 7;
            actT[hh * 233 + rr * 58 + px] =
                *(const v4i*)(asrc + ((size_t)rr * PADH + px) * 256 + h * 128 + hh * 16);
        }
        if (h == 0) {
            // prologue: stage g=0 (kts 0,1) into slot 0 (own chunks)
            #pragma unroll
            for (int j = 0; j < 2; ++j) {
                const char* src = wgb + (size_t)j * 8192;
                char* dstb = (char*)&wring[0][0] + j * 8192;
                gll16(src + c0 * 1024 + lane * 16, dstb + c0 * 1024 + lane * 16);
                gll16(src + c1 * 1024 + lane * 16, dstb + c1 * 1024 + lane * 16);
            }
        }
        __syncthreads();                  // acts + staged weights drained

        #pragma unroll 1
        for (int it = 0; it < 18; ++it) {
            int g = h * 18 + it;
            int gn = g + 1 > 35 ? 35 : g + 1;       // g=17 stages g=18 (h=1 it=0)
            // stage next iteration's 2 kts into slot (g+1)&1 (own chunks)
            {
                char* dstb = (char*)&wring[(g + 1) & 1][0];
                #pragma unroll
                for (int j = 0; j < 2; ++j) {
                    int kt = (gn / 18) * 36 + (gn % 18) * 2 + j;
                    const char* src = wgb + (size_t)kt * 8192;
                    char* db = dstb + j * 8192;
                    gll16(src + c0 * 1024 + lane * 16, db + c0 * 1024 + lane * 16);
                    gll16(src + c1 * 1024 + lane * 16, db + c1 * 1024 + lane * 16);
                }
            }
            asm volatile("s_waitcnt vmcnt(4)" ::: "memory");
            const v4i* wr = &wring[g & 1][0];
            int tap = it >> 1;
            int doff = (tap / 3) * 58 + tap % 3 - 59;
            __builtin_amdgcn_s_setprio(1);
            #pragma unroll
            for (int j = 0; j < 2; ++j) {
                int kk = (it & 1) * 2 + j;
                v4i wf0 = wr[(j * 8 + c0) * 64 + lane];
                v4i wf1 = wr[(j * 8 + c1) * 64 + lane];
                int hb = (kk * 2 + half) * 233 + doff;
                v4i af0 = actT[hb + pidx[0]];
                v4i af1 = actT[hb + pidx[1]];
                v4i af2 = actT[hb + pidx[2]];
                v4i af3 = actT[hb + pidx[3]];
                if (CONV1) {
                    acc[0] = __builtin_amdgcn_mfma_i32_32x32x32_i8(wf0, af0, acc[0], 0, 0, 0);
                    acc[1] = __builtin_amdgcn_mfma_i32_32x32x32_i8(wf0, af1, acc[1], 0, 0, 0);
                    acc[2] = __builtin_amdgcn_mfma_i32_32x32x32_i8(wf0, af2, acc[2], 0, 0, 0);
                    acc[3] = __builtin_amdgcn_mfma_i32_32x32x32_i8(wf0, af3, acc[3], 0, 0, 0);
                    acc[4] = __builtin_amdgcn_mfma_i32_32x32x32_i8(wf1, af0, acc[4], 0, 0, 0);
                    acc[5] = __builtin_amdgcn_mfma_i32_32x32x32_i8(wf1, af1, acc[5], 0, 0, 0);
                    acc[6] = __builtin_amdgcn_mfma_i32_32x32x32_i8(wf1, af2, acc[6], 0, 0, 0);
                    acc[7] = __builtin_amdgcn_mfma_i32_32x32x32_i8(wf1, af3, acc[7], 0, 0, 0);
                } else {
                    acc[0] = __builtin_amdgcn_mfma_i32_32x32x32_i8(af0, wf0, acc[0], 0, 0, 0);
                    acc[1] = __builtin_amdgcn_mfma_i32_32x32x32_i8(af1, wf0, acc[1], 0, 0, 0);
                    acc[2] = __builtin_amdgcn_mfma_i32_32x32x32_i8(af2, wf0, acc[2], 0, 0, 0);
                    acc[3] = __builtin_amdgcn_mfma_i32_32x32x32_i8(af3, wf0, acc[3], 0, 0, 0);
                    acc[4] = __builtin_amdgcn_mfma_i32_32x32x32_i8(af0, wf1, acc[4], 0, 0, 0);
                    acc[5] = __builtin_amdgcn_mfma_i32_32x32x32_i8(af1, wf1, acc[5], 0, 0, 0);
                    acc[6] = __builtin_amdgcn_mfma_i32_32x32x32_i8(af2, wf1, acc[6], 0, 0, 0);
                    acc[7] = __builtin_amdgcn_mfma_i32_32x32x32_i8(af3, wf1, acc[7], 0, 0, 0);
                }
            }
            __builtin_amdgcn_s_setprio(0);
        }
    }
    // pending tail gll16s only rewrite wring with identical data; no drain needed

    if (!CONV1) {
        int pbase = n * HW + y0 * 56;
        #pragma unroll
        for (int ci = 0; ci < 2; ++ci) {
            int co = (wave + ci * 4) * 32 + l31;
            long long ssum = 0, ssq = 0;
            #pragma unroll
            for (int m = 0; m < 4; ++m) {
                v16i a = acc[ci * 4 + m];
                #pragma unroll
                for (int r = 0; r < 16; ++r) {
                    int prow = (r & 3) + ((r >> 2) << 3) + (half << 2);
                    int s = m * 32 + prow;
                    int rr = s >> 6, col = s & 63;
                    if (col < 56) {
                        Cout[(size_t)(pbase + rr * 56 + col) * 256 + co] =
                            (short)((a[r] + 8) >> 4);
                        ssum += a[r];
                        ssq  += (long long)a[r] * a[r];
                    }
                }
            }
            ssum += __shfl_xor(ssum, 32);
            ssq  += __shfl_xor(ssq, 32);
            if (half == 0) {
                atomicAdd(&sums[co], (unsigned long long)ssum);
                atomicAdd(&sums[256 + co], (unsigned long long)ssq);
            }
        }
    } else {
        #pragma unroll
        for (int m = 0; m < 4; ++m) {
            int s = m * 32 + l31;
            int rr = s >> 6, col = s & 63;
            if (col < 56) {
                size_t boff = (size_t)n * NCH * HW + (size_t)(y0 + rr) * 56 + col;
                #pragma unroll
                for (int ci = 0; ci < 2; ++ci) {
                    v16i a = acc[ci * 4 + m];
                    #pragma unroll
                    for (int r = 0; r < 16; ++r) {
                        int prow = (r & 3) + ((r >> 2) << 3) + (half << 2);
                        int co = (wave + ci * 4) * 32 + prow;
                        size_t off = boff + (size_t)co * HW;
                        Out[off] = fmaf(s1, (float)a[r], Xin[off]);
                    }
                }
            }
        }
    }
}

__global__ void bn1_finalize(const unsigned long long* __restrict__ sums,
        const float* __restrict__ g, const float* __restrict__ b,
        const float* __restrict__ scale0p, float* __restrict__ A1, float* __restrict__ B1) {
    int c = threadIdx.x;
    double sc0 = (double)*scale0p;
    double S  = (double)(long long)sums[c];
    double S2 = (double)(long long)sums[256 + c];
    double meanS = S / (double)NPIX;
    double varS  = S2 / (double)NPIX - meanS * meanS;
    float meanf = (float)(sc0 * meanS);
    float varf  = (float)(sc0 * sc0 * varS);
    float rstd = (float)(1.0 / sqrt((double)varf + 1e-5));
    float gc = g[c], bc = b[c];
    A1[c] = (float)(sc0 * (double)rstd * (double)gc * 16.0);  // x16: int16 stored (s+8)>>4
    B1[c] = bc - meanf * rstd * gc;
}

// requantize conv0 int16 output -> padded NHWC int8 (reuses act buffer; halo still zero)
__global__ __launch_bounds__(256) void quant1(const short* __restrict__ Cin,
        const float* __restrict__ A1, const float* __restrict__ B1,
        int8_t* __restrict__ A) {
    int idx = blockIdx.x * 256 + threadIdx.x;
    int e4 = idx * 4;
    if (e4 >= NPIX * 256) return;
    int p = e4 >> 8, c4 = e4 & 255;
    int n = p / HW, r2 = p % HW, y = r2 / 56, xx = r2 % 56;
    const short4 v = *(const short4*)(Cin + e4);
    short vv[4] = {v.x, v.y, v.z, v.w};
    unsigned char qq[4];
    #pragma unroll
    for (int j = 0; j < 4; ++j) {
        float y1 = fmaf((float)vv[j], A1[c4 + j], B1[c4 + j]);
        y1 = fminf(fmaxf(y1, 0.f), 1.f);
        qq[j] = (unsigned char)(int)rintf(y1 * 15.f);
    }
    uchar4 q; q.x = qq[0]; q.y = qq[1]; q.z = qq[2]; q.w = qq[3];
    size_t dst = (((size_t)n * PADH + y + 1) * PADH + xx + 1) * 256 + c4;
    *(uchar4*)(A + dst) = q;
}

extern "C" void kernel_launch(void* const* d_in, const int* in_sizes, int n_in,
                              void* d_out, int out_size, void* d_ws, size_t ws_size,
                              hipStream_t stream) {
    const float* x  = (const float*)d_in[0];
    const float* g0 = (const float*)d_in[1];
    const float* b0 = (const float*)d_in[2];
    const float* w0 = (const float*)d_in[3];
    const float* g1 = (const float*)d_in[4];
    const float* b1 = (const float*)d_in[5];
    const float* w1 = (const float*)d_in[6];
    float* out = (float*)d_out;

    char* ws = (char*)d_ws;
    int8_t* a0 = (int8_t*)(ws + A0_OFF);
    v4i* wp0 = (v4i*)(ws + WP0_OFF);
    v4i* wp1 = (v4i*)(ws + WP1_OFF);
    float* coef = (float*)(ws + COEF_OFF);
    float* A0c = coef;       float* B0c = coef + 256;
    float* A1c = coef + 512; float* B1c = coef + 768;
    float* scales = coef + 1024;             // [0]=scale0 [1]=scale1
    unsigned* maxw = (unsigned*)(ws + MAXW_OFF);
    unsigned long long* sums = (unsigned long long*)(ws + SUM1_OFF);
    double2* part = (double2*)(ws + PART_OFF);

    short* c0 = (short*)d_out;   // conv0 int16 sums live in d_out until conv1 overwrites

    hipMemsetAsync(a0, 0, A0_BYTES, stream);
    bn0_part<<<4096, 256, 0, stream>>>(x, part, maxw, sums);
    bn0_final<<<1, 256, 0, stream>>>(part, g0, b0, A0c, B0c);
    quant0<<<dim3(56, 16), 256, 0, stream>>>(x, A0c, B0c, a0);
    wmax2<<<dim3(256, 2), 256, 0, stream>>>(w0, w1, maxw);
    wpack2<<<dim3(128, 2), 256, 0, stream>>>(w0, w1, maxw, (int8_t*)wp0, (int8_t*)wp1, scales);
    conv_mfma<0><<<dim3(28, 16), 256, 0, stream>>>(a0, wp0, c0, sums, nullptr, nullptr, nullptr);
    bn1_finalize<<<1, 256, 0, stream>>>(sums, g1, b1, scales, A1c, B1c);
    quant1<<<12544, 256, 0, stream>>>(c0, A1c, B1c, a0);
    conv_mfma<1><<<dim3(28, 16), 256, 0, stream>>>(a0, wp1, nullptr, nullptr, scales + 1, x, out);
}